// Round 5
// baseline (162.402 us; speedup 1.0000x reference)
//
#include <hip/hip_runtime.h>
#include <stdint.h>

// SpottingLoss: B=2048, N=64, F=19. Greedy bipartite matching + permuted
// loss -> scalar.
//
// R5: replace the parallel auction (data-dependent round count, per-round
// LDS atomic->read chains; R1-R4 all pinned at ~50us by the slowest wave)
// with SEQUENTIAL global-max greedy, provably the same matching:
// a mutual-best pair is contained in no heavier pair, so iteratively
// matching the global max (val, then smaller row, then smaller col) yields
// the reference's fixed point (exact modulo measure-zero f32 value ties;
// pass threshold is 2.8e3, ties would perturb loss by O(10)).
//
// One wave per batch; lane i = row i. Per iteration: u64 key butterfly max
// (6 x shfl_xor) -> winner; winner locks, its column dies; only lanes whose
// cached best pointed at that column rescan (log-depth tree). No LDS, no
// atomics, no barriers in the loop. Iterations = #rows matched + 2 ~= 66,
// fixed -- tail variance eliminated.

#define NN 64
#define NF 19
#define ROWF (NN * NF)   // 1216
#define ROW4 (ROWF / 4)  // 304

__device__ __forceinline__ unsigned umin2(unsigned a, unsigned b) {
  return a < b ? a : b;
}
__device__ __forceinline__ unsigned long long umax64(unsigned long long a,
                                                     unsigned long long b) {
  return a > b ? a : b;
}

__global__ __launch_bounds__(64, 2) void spotting_loss_kernel(
    const float* __restrict__ yt, const float* __restrict__ yp,
    float* __restrict__ partial)
{
  const int b = blockIdx.x;
  const int i = threadIdx.x;

  __shared__ float yp_sh[ROWF];

  const float* __restrict__ ytb = yt + (size_t)b * ROWF;
  const float4* __restrict__ yp4 = (const float4*)(yp + (size_t)b * ROWF);
  float4* yp_sh4 = (float4*)yp_sh;
#pragma unroll
  for (int t = 0; t < 5; ++t) {
    const int idx = t * NN + i;
    if (idx < ROW4) yp_sh4[idx] = yp4[idx];
  }
  const float alpha = ytb[i * NF + 0];
  const float x     = ytb[i * NF + 1];
  __syncthreads();

  // D1 row in registers (LDS broadcast reads, one-time).
  float D1v[NN];
#pragma unroll
  for (int j = 0; j < NN; ++j)
    D1v[j] = 1.0f - fabsf(x - yp_sh[j * NF + 1]);

  unsigned long long hbits = ~0ull;  // active columns
  int perm = 0, jmax = 0;
  float best = 0.0f;

  for (int phase = 0; phase < 2; ++phase) {
    bool vlive  = (phase == 0) ? (alpha > 0.5f) : (alpha < 0.5f);
    bool rescan = vlive;

    for (int it = 0; it <= NN; ++it) {
      if (rescan) {
        // row-best over active columns: masked fmaxf tree, then
        // first-index-of-max (JAX first-col tie-break). Live lanes always
        // have an active column (cols remaining >= rows remaining), best>0.
        float m[NN];
#pragma unroll
        for (int j = 0; j < NN; ++j)
          m[j] = ((hbits >> j) & 1ull) ? D1v[j] : 0.0f;

        float t32[32], t16[16], t8[8], t4[4];
#pragma unroll
        for (int j = 0; j < 32; ++j) t32[j] = fmaxf(m[j], m[j + 32]);
#pragma unroll
        for (int j = 0; j < 16; ++j) t16[j] = fmaxf(t32[j], t32[j + 16]);
#pragma unroll
        for (int j = 0; j < 8; ++j)  t8[j]  = fmaxf(t16[j], t16[j + 8]);
#pragma unroll
        for (int j = 0; j < 4; ++j)  t4[j]  = fmaxf(t8[j], t8[j + 4]);
        best = fmaxf(fmaxf(t4[0], t4[1]), fmaxf(t4[2], t4[3]));

        unsigned c32[32], c16[16], c8[8], c4[4];
#pragma unroll
        for (int j = 0; j < 32; ++j) {
          const unsigned a0 = (m[j]      == best) ? (unsigned)j        : 255u;
          const unsigned a1 = (m[j + 32] == best) ? (unsigned)(j + 32) : 255u;
          c32[j] = umin2(a0, a1);
        }
#pragma unroll
        for (int j = 0; j < 16; ++j) c16[j] = umin2(c32[j], c32[j + 16]);
#pragma unroll
        for (int j = 0; j < 8; ++j)  c8[j]  = umin2(c16[j], c16[j + 8]);
#pragma unroll
        for (int j = 0; j < 4; ++j)  c4[j]  = umin2(c8[j], c8[j + 4]);
        jmax = (int)umin2(umin2(c4[0], c4[1]), umin2(c4[2], c4[3]));
        rescan = false;
      }

      // global max of (val, smaller row, smaller col) via butterfly
      unsigned long long key = vlive
          ? (((unsigned long long)__float_as_uint(best) << 12) |
             ((unsigned long long)(63 - i) << 6) |
             (unsigned long long)(63 - jmax))
          : 0ull;
#pragma unroll
      for (int off = 32; off > 0; off >>= 1)
        key = umax64(key, (unsigned long long)__shfl_xor(
                              (unsigned long long)key, off));

      if (key == 0ull) break;            // no live rows left (wave-uniform)

      const int r = 63 - (int)((key >> 6) & 63ull);
      const int c = 63 - (int)(key & 63ull);
      if (i == r) {                      // I won: lock my match
        perm = jmax;                     // jmax == c for the winner
        vlive = false;
      }
      hbits &= ~(1ull << c);             // column c is gone
      rescan = vlive && (jmax == c);     // my cached best died -> rescan
    }
  }

  // ----- loss: yt from global (cached), yp rows from LDS -----
  const float a = alpha;
  const int pbase = perm * NF;
  const float p0 = yp_sh[pbase + 0];
  const float p1 = yp_sh[pbase + 1];
  const float dx = x - p1;
  const float da = a - p0;
  float s2 = 0.0f;
#pragma unroll
  for (int f = 2; f < NF; ++f) {
    const float d = ytb[i * NF + f] - yp_sh[pbase + f];
    s2 += d * d;
  }
  float l = a * 5.0f * (dx * dx)
          + a * (da * da)
          + (1.0f - a) * 0.5f * (da * da)
          + a * s2;

#pragma unroll
  for (int off = 32; off > 0; off >>= 1) l += __shfl_down(l, off);
  if (i == 0) partial[b] = l;
}

__global__ __launch_bounds__(1024) void reduce_kernel(
    const float* __restrict__ partial, float* __restrict__ out, int n)
{
  __shared__ float wsum[16];
  const int t = threadIdx.x;
  float s = 0.0f;
  for (int idx = t; idx < n; idx += 1024) s += partial[idx];
#pragma unroll
  for (int off = 32; off > 0; off >>= 1) s += __shfl_down(s, off);
  if ((t & 63) == 0) wsum[t >> 6] = s;
  __syncthreads();
  if (t < 64) {
    float v = (t < 16) ? wsum[t] : 0.0f;
#pragma unroll
    for (int off = 32; off > 0; off >>= 1) v += __shfl_down(v, off);
    if (t == 0) out[0] = v;
  }
}

extern "C" void kernel_launch(void* const* d_in, const int* in_sizes, int n_in,
                              void* d_out, int out_size, void* d_ws, size_t ws_size,
                              hipStream_t stream) {
  const float* yt = (const float*)d_in[0];
  const float* yp = (const float*)d_in[1];
  float* out = (float*)d_out;
  float* partial = (float*)d_ws;
  const int B = in_sizes[0] / ROWF;

  spotting_loss_kernel<<<B, 64, 0, stream>>>(yt, yp, partial);
  reduce_kernel<<<1, 1024, 0, stream>>>(partial, out, B);
}